// Round 4
// baseline (577.649 us; speedup 1.0000x reference)
//
#include <hip/hip_runtime.h>
#include <hip/hip_fp16.h>
#include <math.h>

#define RES 128
#define NPROBE 256
#define TEXELS (NPROBE * 6 * RES * RES)          // 25,165,824 texels
#define TAB_BYTES ((size_t)TEXELS * 8)           // 201,326,592 B (8 B/texel: c0,c1,c2,pad fp16)

__device__ __forceinline__ unsigned int packh2(float lo, float hi) {
    union { __half2 h; unsigned int u; } cvt;
    cvt.h = __halves2half2(__float2half_rn(lo), __float2half_rn(hi));
    return cvt.u;
}
__device__ __forceinline__ float2 unpackh2(unsigned int v) {
    union { unsigned int u; __half2 h; } cvt; cvt.u = v;
    return __half22float2(cvt.h);
}

// ---- pass 1: fp32 table -> padded fp16 table in d_ws (streaming) ----
__global__ __launch_bounds__(256) void convert_kernel(
    const float* __restrict__ base, uint4* __restrict__ tab)
{
    int t = blockIdx.x * blockDim.x + threadIdx.x;   // one thread = 4 texels
    if (t >= TEXELS / 4) return;
    const float4* src = (const float4*)base + (size_t)t * 3;
    float4 a = src[0], b = src[1], c = src[2];
    // texels: (a.x,a.y,a.z) (a.w,b.x,b.y) (b.z,b.w,c.x) (c.y,c.z,c.w)
    uint4 w0, w1;
    w0.x = packh2(a.x, a.y); w0.y = packh2(a.z, 0.0f);
    w0.z = packh2(a.w, b.x); w0.w = packh2(b.y, 0.0f);
    w1.x = packh2(b.z, b.w); w1.y = packh2(c.x, 0.0f);
    w1.z = packh2(c.y, c.z); w1.w = packh2(c.w, 0.0f);
    tab[(size_t)t * 2]     = w0;
    tab[(size_t)t * 2 + 1] = w1;
}

// ---- pass 2: gather from the (L3-resident) fp16 table ----
__global__ __launch_bounds__(256) void gather_h_kernel(
    const float* __restrict__ xyz, const float* __restrict__ l,
    const uint2* __restrict__ tab, float* __restrict__ out, int n)
{
    int i = blockIdx.x * blockDim.x + threadIdx.x;
    if (i >= n) return;

    // direction
    float lx = l[3*i+0], ly = l[3*i+1], lz = l[3*i+2];
    float inv = 1.0f / fmaxf(sqrtf(lx*lx + ly*ly + lz*lz), 1e-9f);
    float dx = lx*inv, dy = ly*inv, dz = lz*inv;

    // cube face / uv
    float ax = fabsf(dx), ay = fabsf(dy), az = fabsf(dz);
    bool is_x = (ax >= ay) && (ax >= az);
    bool is_y = (!is_x) && (ay >= az);
    int face; float ma, sc, tc;
    if (is_x) { face = (dx >= 0.0f) ? 0 : 1; ma = ax; sc = (dx >= 0.0f) ? -dz : dz; tc = -dy; }
    else if (is_y) { face = (dy >= 0.0f) ? 2 : 3; ma = ay; sc = dx; tc = (dy >= 0.0f) ? dz : -dz; }
    else { face = (dz >= 0.0f) ? 4 : 5; ma = az; sc = (dz >= 0.0f) ? dx : -dx; tc = -dy; }
    ma = fmaxf(ma, 1e-9f);
    float u = 0.5f * (sc / ma + 1.0f);
    float v = 0.5f * (tc / ma + 1.0f);

    // bilinear coords
    float fx = u * (float)RES - 0.5f;
    float fy = v * (float)RES - 0.5f;
    float x0f = floorf(fx), y0f = floorf(fy);
    float tx = fx - x0f, ty = fy - y0f;
    int xi = (int)x0f, yi = (int)y0f;
    int y0 = min(max(yi,     0), RES-1);
    int y1 = min(max(yi + 1, 0), RES-1);
    // x handled as an adjacent pair [ps, ps+1] with remapped weights (clamp-safe)
    int ps = min(max(xi, 0), RES-2);
    int x0 = min(max(xi,     0), RES-1);
    int x1 = min(xi + 1, RES-1);
    float wl = ((x0 == ps) ? (1.0f - tx) : 0.0f) + ((x1 == ps) ? tx : 0.0f);
    float wr = 1.0f - wl;

    // trilinear probe corners
    float px = xyz[3*i+0], py = xyz[3*i+1], pz = xyz[3*i+2];
    float cx = fminf(fmaxf(px * 7.0f, 0.0f), 7.0f);
    float cy = fminf(fmaxf(py * 7.0f, 0.0f), 7.0f);
    float cz = fminf(fmaxf(pz * 3.0f, 0.0f), 3.0f);
    int ix0 = (int)floorf(cx), iy0 = (int)floorf(cy), iz0 = (int)floorf(cz);
    int ix1 = min(ix0 + 1, 7), iy1 = min(iy0 + 1, 7), iz1 = min(iz0 + 1, 3);
    float tgx = cx - (float)ix0, tgy = cy - (float)iy0, tgz = cz - (float)iz0;
    float wx[2] = {1.0f - tgx, tgx};
    float wy[2] = {1.0f - tgy, tgy};
    float wz[2] = {1.0f - tgz, tgz};
    int   gx[2] = {ix0, ix1}, gy2[2] = {iy0, iy1}, gz[2] = {iz0, iz1};

    float pw[8]; int pidx[8]; float wsum = 0.0f;
    #pragma unroll
    for (int ox = 0; ox < 2; ++ox)
      #pragma unroll
      for (int oy = 0; oy < 2; ++oy)
        #pragma unroll
        for (int oz = 0; oz < 2; ++oz) {
            int p = ox*4 + oy*2 + oz;
            float w = wx[ox] * wy[oy] * wz[oz];
            pw[p] = w; wsum += w;
            pidx[p] = gx[ox]*32 + gy2[oy]*4 + gz[oz];
        }
    float winv = 1.0f / fmaxf(wsum, 1e-8f);

    int roff[2] = { face * (RES*RES) + y0 * RES + ps,
                    face * (RES*RES) + y1 * RES + ps };
    float rw[2] = { 1.0f - ty, ty };

    // PHASE 1: issue all 32 8-byte texel loads (16 row-pairs x {left,right})
    uint2 tex[8][2][2];   // [probe][row][l/r]
    #pragma unroll
    for (int p = 0; p < 8; ++p) {
        size_t pb = (size_t)pidx[p] * (6 * RES * RES);
        #pragma unroll
        for (int r = 0; r < 2; ++r) {
            size_t e = pb + (size_t)roff[r];
            tex[p][r][0] = tab[e];
            tex[p][r][1] = tab[e + 1];
        }
    }
    __builtin_amdgcn_sched_barrier(0);

    // PHASE 2: blend
    float acc0 = 0.0f, acc1 = 0.0f, acc2 = 0.0f;
    #pragma unroll
    for (int p = 0; p < 8; ++p) {
        #pragma unroll
        for (int r = 0; r < 2; ++r) {
            float w = pw[p] * rw[r];
            float2 l01 = unpackh2(tex[p][r][0].x);
            float2 l2_ = unpackh2(tex[p][r][0].y);
            float2 r01 = unpackh2(tex[p][r][1].x);
            float2 r2_ = unpackh2(tex[p][r][1].y);
            acc0 += w * (wl * l01.x + wr * r01.x);
            acc1 += w * (wl * l01.y + wr * r01.y);
            acc2 += w * (wl * l2_.x + wr * r2_.x);
        }
    }
    acc0 *= winv; acc1 *= winv; acc2 *= winv;

    out[3*i+0] = 10.0f / (1.0f + __expf(-acc0));
    out[3*i+1] = 10.0f / (1.0f + __expf(-acc1));
    out[3*i+2] = 10.0f / (1.0f + __expf(-acc2));
}

// ---- fallback: round-0 direct fp32 kernel (used if ws too small) ----
__global__ __launch_bounds__(256) void mel_fp32_kernel(
    const float* __restrict__ xyz, const float* __restrict__ l,
    const float* __restrict__ base, float* __restrict__ out, int n)
{
    int i = blockIdx.x * blockDim.x + threadIdx.x;
    if (i >= n) return;
    float lx = l[3*i+0], ly = l[3*i+1], lz = l[3*i+2];
    float inv = 1.0f / fmaxf(sqrtf(lx*lx + ly*ly + lz*lz), 1e-9f);
    float dx = lx*inv, dy = ly*inv, dz = lz*inv;
    float ax = fabsf(dx), ay = fabsf(dy), az = fabsf(dz);
    bool is_x = (ax >= ay) && (ax >= az);
    bool is_y = (!is_x) && (ay >= az);
    int face; float ma, sc, tc;
    if (is_x) { face = (dx >= 0.0f) ? 0 : 1; ma = ax; sc = (dx >= 0.0f) ? -dz : dz; tc = -dy; }
    else if (is_y) { face = (dy >= 0.0f) ? 2 : 3; ma = ay; sc = dx; tc = (dy >= 0.0f) ? dz : -dz; }
    else { face = (dz >= 0.0f) ? 4 : 5; ma = az; sc = (dz >= 0.0f) ? dx : -dx; tc = -dy; }
    ma = fmaxf(ma, 1e-9f);
    float u = 0.5f * (sc / ma + 1.0f);
    float v = 0.5f * (tc / ma + 1.0f);
    float fx = u * (float)RES - 0.5f;
    float fy = v * (float)RES - 0.5f;
    float x0f = floorf(fx), y0f = floorf(fy);
    float tx = fx - x0f, ty = fy - y0f;
    int x0 = min(max((int)x0f,     0), RES-1);
    int x1 = min(max((int)x0f + 1, 0), RES-1);
    int y0 = min(max((int)y0f,     0), RES-1);
    int y1 = min(max((int)y0f + 1, 0), RES-1);
    float px = xyz[3*i+0], py = xyz[3*i+1], pz = xyz[3*i+2];
    float cx = fminf(fmaxf(px * 7.0f, 0.0f), 7.0f);
    float cy = fminf(fmaxf(py * 7.0f, 0.0f), 7.0f);
    float cz = fminf(fmaxf(pz * 3.0f, 0.0f), 3.0f);
    int ix0 = (int)floorf(cx), iy0 = (int)floorf(cy), iz0 = (int)floorf(cz);
    int ix1 = min(ix0 + 1, 7), iy1 = min(iy0 + 1, 7), iz1 = min(iz0 + 1, 3);
    float tgx = cx - (float)ix0, tgy = cy - (float)iy0, tgz = cz - (float)iz0;
    float wx[2] = {1.0f - tgx, tgx};
    float wy[2] = {1.0f - tgy, tgy};
    float wz[2] = {1.0f - tgz, tgz};
    int   gx[2] = {ix0, ix1}, gy[2] = {iy0, iy1}, gz[2] = {iz0, iz1};
    float pw[8]; int pidx[8]; float wsum = 0.0f;
    #pragma unroll
    for (int ox = 0; ox < 2; ++ox)
      #pragma unroll
      for (int oy = 0; oy < 2; ++oy)
        #pragma unroll
        for (int oz = 0; oz < 2; ++oz) {
            int p = ox*4 + oy*2 + oz;
            float w = wx[ox] * wy[oy] * wz[oz];
            pw[p] = w; wsum += w;
            pidx[p] = gx[ox]*32 + gy[oy]*4 + gz[oz];
        }
    float winv = 1.0f / fmaxf(wsum, 1e-8f);
    int toff[4] = { y0*RES + x0, y0*RES + x1, y1*RES + x0, y1*RES + x1 };
    float bw[4] = { (1.0f-ty)*(1.0f-tx), (1.0f-ty)*tx, ty*(1.0f-tx), ty*tx };
    int face_off = face * (RES * RES);
    float acc0 = 0.0f, acc1 = 0.0f, acc2 = 0.0f;
    #pragma unroll
    for (int p = 0; p < 8; ++p) {
        const float* bp = base + (size_t)(pidx[p] * (6 * RES * RES) + face_off) * 3;
        #pragma unroll
        for (int t = 0; t < 4; ++t) {
            const float* a = bp + toff[t] * 3;
            float wt = pw[p] * bw[t];
            acc0 += wt * a[0]; acc1 += wt * a[1]; acc2 += wt * a[2];
        }
    }
    acc0 *= winv; acc1 *= winv; acc2 *= winv;
    out[3*i+0] = 10.0f / (1.0f + __expf(-acc0));
    out[3*i+1] = 10.0f / (1.0f + __expf(-acc1));
    out[3*i+2] = 10.0f / (1.0f + __expf(-acc2));
}

extern "C" void kernel_launch(void* const* d_in, const int* in_sizes, int n_in,
                              void* d_out, int out_size, void* d_ws, size_t ws_size,
                              hipStream_t stream) {
    const float* xyz  = (const float*)d_in[0];
    const float* l    = (const float*)d_in[1];
    const float* base = (const float*)d_in[2];
    float* out = (float*)d_out;
    int n = in_sizes[0] / 3;
    int blocks = (n + 255) / 256;

    if (ws_size >= TAB_BYTES) {
        int cblocks = (TEXELS / 4 + 255) / 256;
        convert_kernel<<<cblocks, 256, 0, stream>>>(base, (uint4*)d_ws);
        gather_h_kernel<<<blocks, 256, 0, stream>>>(xyz, l, (const uint2*)d_ws, out, n);
    } else {
        mel_fp32_kernel<<<blocks, 256, 0, stream>>>(xyz, l, base, out, n);
    }
}